// Round 14
// baseline (392.153 us; speedup 1.0000x reference)
//
#include <hip/hip_runtime.h>
#include <hip/hip_bf16.h>
#include <stdint.h>

// ---------------------------------------------------------------------------
// GPT-2 block on MI355X (gfx950). Round 14:
//  - QKV/FC: 256x256 4-phase dbuf GEMM (m201-style), register budget fixed:
//    only current-kk b[4] cached (round 9's b0+b1 caching pushed unified regs
//    past 256 -> 1 wave/SIMD, Occupancy 10.7%). __launch_bounds__(512,2)
//    forces 2 waves/SIMD. Counted vmcnt(4) at tile boundary.
//  - Wo/Proj stay bt6 (grid 512); attn/LN/transpose from the 373us state.
// ---------------------------------------------------------------------------

typedef short bf16x8 __attribute__((ext_vector_type(8)));
typedef float f32x4  __attribute__((ext_vector_type(4)));
typedef float f32x16 __attribute__((ext_vector_type(16)));
typedef short s16x4  __attribute__((ext_vector_type(4)));

__device__ __forceinline__ short f2bf(float f) {
  union { float f; uint32_t u; } a;
  a.f = f;
  uint32_t r = a.u + 0x7fffu + ((a.u >> 16) & 1u);  // RNE
  return (short)(r >> 16);
}

__device__ __forceinline__ unsigned cvt_pk_bf16(float lo, float hi_) {
  unsigned r;
  asm("v_cvt_pk_bf16_f32 %0, %1, %2" : "=v"(r) : "v"(lo), "v"(hi_));
  return r;
}

__device__ __forceinline__ float ex2(float x) {   // D = 2^x, raw HW op
  float r;
  asm("v_exp_f32 %0, %1" : "=v"(r) : "v"(x));
  return r;
}

__device__ __forceinline__ float rcp(float x) {
  float r;
  asm("v_rcp_f32 %0, %1" : "=v"(r) : "v"(x));
  return r;
}

__device__ __forceinline__ float m3(float a, float b, float c) {
  return fmaxf(fmaxf(a, b), c);   // clang fuses to v_max3_f32
}

__device__ __forceinline__ void gload_lds16(const void* g, void* l) {
  __builtin_amdgcn_global_load_lds(
      (const __attribute__((address_space(1))) void*)g,
      (__attribute__((address_space(3))) void*)l, 16, 0, 0);
}

__device__ __forceinline__ float gelu_f(float x) {
  float y = 0.7978845608028654f * (x + 0.044715f * x * x * x);
  y = fminf(fmaxf(y, -20.f), 20.f);
  float e = __expf(2.f * y);
  return 0.5f * x * (1.f + (e - 1.f) / (e + 1.f));  // tanh via exp
}

// ---------------------- merged weight fp32 -> bf16 --------------------------
struct W6 {
  const float* s[6];
  short* d[6];
  int off[7];   // prefix offsets in float4 units
};

__global__ __launch_bounds__(256)
void cvt_all(W6 a) {
  const int i = blockIdx.x * 256 + threadIdx.x;
#pragma unroll
  for (int k = 0; k < 6; ++k) {
    if (i >= a.off[k] && i < a.off[k + 1]) {
      const int j = i - a.off[k];
      float4 v = ((const float4*)a.s[k])[j];
      s16x4 o;
      o[0] = f2bf(v.x); o[1] = f2bf(v.y); o[2] = f2bf(v.z); o[3] = f2bf(v.w);
      ((s16x4*)a.d[k])[j] = o;
    }
  }
}

// ------------------------------- LayerNorm ---------------------------------
__global__ __launch_bounds__(256)
void ln_fwd(const float* __restrict__ x, const float* __restrict__ g,
            const float* __restrict__ b, short* __restrict__ y) {
  const long row = blockIdx.x;
  const int t = threadIdx.x;
  const float4 xv = ((const float4*)(x + row * 1024))[t];
  float s  = xv.x + xv.y + xv.z + xv.w;
  float ss = xv.x * xv.x + xv.y * xv.y + xv.z * xv.z + xv.w * xv.w;
#pragma unroll
  for (int m = 1; m < 64; m <<= 1) {
    s  += __shfl_xor(s, m);
    ss += __shfl_xor(ss, m);
  }
  __shared__ float rs[4], rss[4];
  const int wid = t >> 6, lane = t & 63;
  if (lane == 0) { rs[wid] = s; rss[wid] = ss; }
  __syncthreads();
  s  = rs[0] + rs[1] + rs[2] + rs[3];
  ss = rss[0] + rss[1] + rss[2] + rss[3];
  const float mu   = s * (1.f / 1024.f);
  const float var  = ss * (1.f / 1024.f) - mu * mu;
  const float rstd = rsqrtf(var + 1e-5f);
  const float4 gv = ((const float4*)g)[t];
  const float4 bv = ((const float4*)b)[t];
  s16x4 ov;
  ov[0] = f2bf((xv.x - mu) * rstd * gv.x + bv.x);
  ov[1] = f2bf((xv.y - mu) * rstd * gv.y + bv.y);
  ov[2] = f2bf((xv.z - mu) * rstd * gv.z + bv.z);
  ov[3] = f2bf((xv.w - mu) * rstd * gv.w + bv.w);
  *(s16x4*)(y + row * 1024 + t * 4) = ov;
}

// ---------- GEMM 256x256 (NT, BK=64, dbuf, 4-phase, reg-budget-safe) --------
// 512 thr / 8 waves (2M x 4N), per-wave 128x64 = acc[2][4][4] (128 AGPR).
// Per phase: 4-8 ds_read_b128, one half-tile stage, barrier, lgkm0, 16 MFMA,
// barrier. b[4] cached only across the (mh0,mh1) pair of its kk. Staging:
// A(t+1) halves at P0/P1 into buf^1; B(t+2) both halves at P3 into buf
// (Bs[buf] last read at P2). Boundary vmcnt(4) keeps B(t+2) in flight.
template <int OUT_BF16, int HAS_RES, int HAS_GELU, int SCALE_Q>
__global__ __launch_bounds__(512, 2)
void gemm256b(const short* __restrict__ A, const short* __restrict__ W,
              const float* __restrict__ bias, const float* __restrict__ res,
              void* __restrict__ out, int M, int N, int K) {
  __shared__ short As[2][256 * 64];
  __shared__ short Bs[2][256 * 64];
  const int tid = threadIdx.x;
  const int wid = tid >> 6, lane = tid & 63;
  const int l16 = lane & 15, lg = lane >> 4;
  const int wm = wid >> 2, wn = wid & 3;       // 2 x 4 wave grid

  const int nbx = N >> 8;
  const int nwg = nbx * (M >> 8);
  int flat = (int)blockIdx.x;
  if ((nwg & 7) == 0) flat = (flat & 7) * (nwg >> 3) + (flat >> 3);
  const int brow = (flat / nbx) * 256, bcol = (flat % nbx) * 256;

  f32x4 acc[2][4][4] = {};                     // [mh][m][n] -> 128 AGPR

  const int r0 = tid >> 3, g0 = tid & 7;

  auto STAGE_A = [&](int buf, int half, int kt) {
#pragma unroll
    for (int i = 0; i < 2; ++i) {
      const int row = half * 128 + i * 64 + r0;
      gload_lds16(A + (long)(brow + row) * K + kt + 8 * (g0 ^ (row & 7)),
                  &As[buf][(half * 1024 + i * 512 + tid) * 8]);
    }
  };
  auto STAGE_B = [&](int buf, int half, int kt) {
#pragma unroll
    for (int i = 0; i < 2; ++i) {
      const int row = half * 128 + i * 64 + r0;
      gload_lds16(W + (long)(bcol + row) * K + kt + 8 * (g0 ^ (row & 7)),
                  &Bs[buf][(half * 1024 + i * 512 + tid) * 8]);
    }
  };

  int ra0[4], ra1[4], rb[4];
#pragma unroll
  for (int m = 0; m < 4; ++m) {
    ra0[m] = wm * 128 + m * 16 + l16;
    ra1[m] = ra0[m] + 64;
  }
#pragma unroll
  for (int n = 0; n < 4; ++n) rb[n] = wn * 64 + n * 16 + l16;

  const int NT = K >> 6;
  // prologue: A(0), B(0) -> buf0; B(1) -> buf1. A(1) staged by t=0's P0/P1.
  STAGE_A(0, 0, 0); STAGE_A(0, 1, 0); STAGE_B(0, 0, 0); STAGE_B(0, 1, 0);
  STAGE_B(1, 0, 64); STAGE_B(1, 1, 64);
  asm volatile("s_waitcnt vmcnt(4)" ::: "memory");   // tile0 landed; B(1) in flight
  __builtin_amdgcn_s_barrier();

  for (int t = 0; t < NT; ++t) {
    const int c = t & 1;
    const bool s1 = (t + 1 < NT), s2 = (t + 2 < NT);
    const int kt1 = (t + 1) << 6, kt2 = (t + 2) << 6;

    bf16x8 a[4], b[4];

    // ---- P0: (kk0, mh0) ----
#pragma unroll
    for (int n = 0; n < 4; ++n)
      b[n] = *(const bf16x8*)&Bs[c][rb[n] * 64 + 8 * (lg ^ (rb[n] & 7))];
#pragma unroll
    for (int m = 0; m < 4; ++m)
      a[m] = *(const bf16x8*)&As[c][ra0[m] * 64 + 8 * (lg ^ (ra0[m] & 7))];
    if (s1) STAGE_A(c ^ 1, 0, kt1);
    __builtin_amdgcn_s_barrier();
    asm volatile("s_waitcnt lgkmcnt(0)" ::: "memory");
    __builtin_amdgcn_sched_barrier(0);
    __builtin_amdgcn_s_setprio(1);
#pragma unroll
    for (int m = 0; m < 4; ++m)
#pragma unroll
      for (int n = 0; n < 4; ++n)
        acc[0][m][n] = __builtin_amdgcn_mfma_f32_16x16x32_bf16(a[m], b[n], acc[0][m][n], 0, 0, 0);
    __builtin_amdgcn_s_setprio(0);
    __builtin_amdgcn_s_barrier();

    // ---- P1: (kk0, mh1), b reused ----
#pragma unroll
    for (int m = 0; m < 4; ++m)
      a[m] = *(const bf16x8*)&As[c][ra1[m] * 64 + 8 * (lg ^ (ra1[m] & 7))];
    if (s1) STAGE_A(c ^ 1, 1, kt1);
    __builtin_amdgcn_s_barrier();
    asm volatile("s_waitcnt lgkmcnt(0)" ::: "memory");
    __builtin_amdgcn_sched_barrier(0);
    __builtin_amdgcn_s_setprio(1);
#pragma unroll
    for (int m = 0; m < 4; ++m)
#pragma unroll
      for (int n = 0; n < 4; ++n)
        acc[1][m][n] = __builtin_amdgcn_mfma_f32_16x16x32_bf16(a[m], b[n], acc[1][m][n], 0, 0, 0);
    __builtin_amdgcn_s_setprio(0);
    __builtin_amdgcn_s_barrier();

    // ---- P2: (kk1, mh0) ----
#pragma unroll
    for (int n = 0; n < 4; ++n)
      b[n] = *(const bf16x8*)&Bs[c][rb[n] * 64 + 8 * ((4 + lg) ^ (rb[n] & 7))];
#pragma unroll
    for (int m = 0; m < 4; ++m)
      a[m] = *(const bf16x8*)&As[c][ra0[m] * 64 + 8 * ((4 + lg) ^ (ra0[m] & 7))];
    __builtin_amdgcn_s_barrier();
    asm volatile("s_waitcnt lgkmcnt(0)" ::: "memory");
    __builtin_amdgcn_sched_barrier(0);
    __builtin_amdgcn_s_setprio(1);
#pragma unroll
    for (int m = 0; m < 4; ++m)
#pragma unroll
      for (int n = 0; n < 4; ++n)
        acc[0][m][n] = __builtin_amdgcn_mfma_f32_16x16x32_bf16(a[m], b[n], acc[0][m][n], 0, 0, 0);
    __builtin_amdgcn_s_setprio(0);
    __builtin_amdgcn_s_barrier();

    // ---- P3: (kk1, mh1); stage B(t+2) into Bs[c] (last read at P2) ----
#pragma unroll
    for (int m = 0; m < 4; ++m)
      a[m] = *(const bf16x8*)&As[c][ra1[m] * 64 + 8 * ((4 + lg) ^ (ra1[m] & 7))];
    if (s2) { STAGE_B(c, 0, kt2); STAGE_B(c, 1, kt2); }
    __builtin_amdgcn_s_barrier();
    asm volatile("s_waitcnt lgkmcnt(0)" ::: "memory");
    __builtin_amdgcn_sched_barrier(0);
    __builtin_amdgcn_s_setprio(1);
#pragma unroll
    for (int m = 0; m < 4; ++m)
#pragma unroll
      for (int n = 0; n < 4; ++n)
        acc[1][m][n] = __builtin_amdgcn_mfma_f32_16x16x32_bf16(a[m], b[n], acc[1][m][n], 0, 0, 0);
    __builtin_amdgcn_s_setprio(0);
    // boundary: A(t+1) (and older) must land; B(t+2) stays in flight
    if (s2)      asm volatile("s_waitcnt vmcnt(4)" ::: "memory");
    else if (s1) asm volatile("s_waitcnt vmcnt(0)" ::: "memory");
    __builtin_amdgcn_s_barrier();
  }

  // epilogue
#pragma unroll
  for (int n = 0; n < 4; ++n) {
    const int col = bcol + wn * 64 + n * 16 + l16;
    const float bb = bias[col];
    const bool doScale = SCALE_Q && (col < N / 3);
#pragma unroll
    for (int mh = 0; mh < 2; ++mh) {
#pragma unroll
      for (int m = 0; m < 4; ++m) {
#pragma unroll
        for (int j = 0; j < 4; ++j) {
          const long row = brow + wm * 128 + mh * 64 + m * 16 + lg * 4 + j;
          float vv = acc[mh][m][n][j] + bb;
          if (HAS_GELU) vv = gelu_f(vv);
          if (HAS_RES) vv += res[row * N + col];
          if (SCALE_Q && doScale) vv *= 0.18033688f;   // 1/8 * log2(e)
          if (OUT_BF16) ((short*)out)[row * N + col] = f2bf(vv);
          else          ((float*)out)[row * N + col] = vv;
        }
      }
    }
  }
}

// -------------- GEMM 128x128 (NT, BK=64, single-buf, 64x64/wave) ------------
template <int OUT_BF16, int HAS_RES, int HAS_GELU>
__global__ __launch_bounds__(256, 2)
void gemm_bt6(const short* __restrict__ A, const short* __restrict__ W,
              const float* __restrict__ bias, const float* __restrict__ res,
              void* __restrict__ out, int M, int N, int K) {
  __shared__ short As[128 * 64];
  __shared__ short Bs[128 * 64];
  const int tid = threadIdx.x;
  const int wid = tid >> 6, lane = tid & 63;
  const int l16 = lane & 15, lg = lane >> 4;
  const int wm = wid >> 1, wn = wid & 1;       // 2 x 2 wave grid

  const int nbx = N >> 7;
  const int nwg = nbx * (M >> 7);
  int flat = (int)blockIdx.x;
  if ((nwg & 7) == 0) flat = (flat & 7) * (nwg >> 3) + (flat >> 3);
  const int brow = (flat / nbx) * 128, bcol = (flat % nbx) * 128;

  f32x4 acc[4][4] = {};

  const int r0 = tid >> 3, g0 = tid & 7;

  int ra[4], rb[4];
#pragma unroll
  for (int m = 0; m < 4; ++m) ra[m] = wm * 64 + m * 16 + l16;
#pragma unroll
  for (int n = 0; n < 4; ++n) rb[n] = wn * 64 + n * 16 + l16;

  for (int kt = 0; kt < K; kt += 64) {
    __syncthreads();
#pragma unroll
    for (int i = 0; i < 4; ++i) {
      const int row = i * 32 + r0;
      gload_lds16(A + (long)(brow + row) * K + kt + 8 * (g0 ^ (row & 7)),
                  &As[(i * 256 + tid) * 8]);
      gload_lds16(W + (long)(bcol + row) * K + kt + 8 * (g0 ^ (row & 7)),
                  &Bs[(i * 256 + tid) * 8]);
    }
    __syncthreads();

#pragma unroll
    for (int kk = 0; kk < 2; ++kk) {
      bf16x8 af[4], bf[4];
#pragma unroll
      for (int m = 0; m < 4; ++m)
        af[m] = *(const bf16x8*)&As[ra[m] * 64 + 8 * ((kk * 4 + lg) ^ (ra[m] & 7))];
#pragma unroll
      for (int n = 0; n < 4; ++n)
        bf[n] = *(const bf16x8*)&Bs[rb[n] * 64 + 8 * ((kk * 4 + lg) ^ (rb[n] & 7))];
#pragma unroll
      for (int m = 0; m < 4; ++m)
#pragma unroll
        for (int n = 0; n < 4; ++n)
          acc[m][n] = __builtin_amdgcn_mfma_f32_16x16x32_bf16(af[m], bf[n], acc[m][n], 0, 0, 0);
    }
  }

#pragma unroll
  for (int n = 0; n < 4; ++n) {
    const int col = bcol + wn * 64 + n * 16 + l16;
    const float bb = bias[col];
#pragma unroll
    for (int m = 0; m < 4; ++m) {
#pragma unroll
      for (int j = 0; j < 4; ++j) {
        const long row = brow + wm * 64 + m * 16 + lg * 4 + j;
        float vv = acc[m][n][j] + bb;
        if (HAS_GELU) vv = gelu_f(vv);
        if (HAS_RES) vv += res[row * N + col];
        if (OUT_BF16) ((short*)out)[row * N + col] = f2bf(vv);
        else          ((float*)out)[row * N + col] = vv;
      }
    }
  }
}

// ------------------------- V transpose (per head) ---------------------------
__global__ __launch_bounds__(256)
void transpose_v(const short* __restrict__ v, short* __restrict__ vtg,
                 int S, int ldv, int H) {
  __shared__ short t[64][66];
  const int bh = blockIdx.y, b = bh / H, hh = bh % H;
  const int s0 = blockIdx.x * 64;
  const int tid = threadIdx.x;
#pragma unroll
  for (int i = 0; i < 2; ++i) {
    const int c = i * 256 + tid;
    const int sl = c >> 3, d8 = (c & 7) * 8;
    bf16x8 vv = *(const bf16x8*)&v[((long)b * S + s0 + sl) * ldv + hh * 64 + d8];
#pragma unroll
    for (int j = 0; j < 8; ++j) t[d8 + j][sl] = vv[j];
  }
  __syncthreads();
#pragma unroll
  for (int i = 0; i < 2; ++i) {
    const int c = i * 256 + tid;
    const int dl = c >> 3, s8 = (c & 7) * 8;
    bf16x8 ov;
#pragma unroll
    for (int j = 0; j < 8; ++j) ov[j] = t[dl][s8 + j];
    *(bf16x8*)&vtg[((long)bh * 64 + dl) * S + s0 + s8] = ov;
  }
}

// --------------------------- causal flash attention -------------------------
__global__ __launch_bounds__(256, 4)
void attn_fwd2(const short* __restrict__ qg, const short* __restrict__ kg,
               const short* __restrict__ vtg, short* __restrict__ og,
               int S, int ldq, int D, int H) {
  const int tid = threadIdx.x, wid = tid >> 6, lane = tid & 63;
  const int l31 = lane & 31, hi = lane >> 5;
  const int fid = blockIdx.x;
  const int bh = fid & 63;
  const int b = bh / H, hh = bh % H;
  static const int perm[16] = {15, 0, 8, 7, 1, 14, 6, 9, 13, 2, 10, 5, 3, 12, 4, 11};
  const int qt = perm[(fid >> 6) & 15];
  const int q0 = qt * 128;
  const long qbase = (long)b * S * ldq + hh * 64;
  const long obase = (long)b * S * D + hh * 64;
  const long vbase = (long)bh * 64 * S;

  __shared__ short Ks[2][64 * 64];
  __shared__ short Vs[2][64 * 64];

  auto STAGE = [&](int buf, int k0) {
#pragma unroll
    for (int i = 0; i < 2; ++i) {
      const int c = i * 256 + tid;
      const int row = c >> 3, gl = c & 7;
      gload_lds16(&kg[qbase + (long)(k0 + row) * ldq + 8 * (gl ^ (row & 7))],
                  &Ks[buf][(i * 256 + wid * 64) * 8]);
      gload_lds16(&vtg[vbase + (long)row * S + k0 + 8 * (gl ^ (row & 7))],
                  &Vs[buf][(i * 256 + wid * 64) * 8]);
    }
  };

  const int qw = q0 + wid * 32;
  const int qv = qw + l31;

  bf16x8 qf[4];
#pragma unroll
  for (int s = 0; s < 4; ++s)
    qf[s] = *(const bf16x8*)&qg[qbase + (long)qv * ldq + 16 * s + 8 * hi];

  f32x16 oa[2] = {};
  float mr = -3000.f, lr = 0.f;

  const int ntiles = qt * 2 + 2;

  STAGE(0, 0);
  for (int t = 0; t < ntiles; ++t) {
    const int cur = t & 1;
    const int k0 = t * 64;
    if (t + 1 < ntiles) {
      STAGE(cur ^ 1, k0 + 64);
      asm volatile("s_waitcnt vmcnt(4)" ::: "memory");
    } else {
      asm volatile("s_waitcnt vmcnt(0)" ::: "memory");
    }
    __builtin_amdgcn_s_barrier();

    if (k0 < qw + 32) {
      f32x16 st[2] = {};
#pragma unroll
      for (int s = 0; s < 4; ++s) {
        const int g = ((s << 1) | hi) ^ (l31 & 7);
        bf16x8 kf0 = *(const bf16x8*)&Ks[cur][l31 * 64 + 8 * g];
        bf16x8 kf1 = *(const bf16x8*)&Ks[cur][(32 + l31) * 64 + 8 * g];
        st[0] = __builtin_amdgcn_mfma_f32_32x32x16_bf16(kf0, qf[s], st[0], 0, 0, 0);
        st[1] = __builtin_amdgcn_mfma_f32_32x32x16_bf16(kf1, qf[s], st[1], 0, 0, 0);
      }

      const bool need_mask = (k0 + 63 > qw);
      float pv[2][16];
#pragma unroll
      for (int kb = 0; kb < 2; ++kb)
#pragma unroll
        for (int r = 0; r < 16; ++r) {
          float v = st[kb][r];           // Q pre-scaled: log2 domain
          if (need_mask) {
            const int key = k0 + kb * 32 + (r & 3) + 8 * (r >> 2) + 4 * hi;
            if (key > qv) v = -1e30f;
          }
          pv[kb][r] = v;
        }

      float rm = fmaxf(pv[0][0], pv[0][1]);
#pragma unroll
      for (int r = 2; r < 16; r += 2) rm = m3(rm, pv[0][r], pv[0][r + 1]);
#pragma unroll
      for (int r = 0; r < 16; r += 2) rm = m3(rm, pv[1][r], pv[1][r + 1]);
      rm = fmaxf(rm, __shfl_xor(rm, 32));

      const bool defer = (bool)__all(rm <= mr + 8.f);
      const float mn = defer ? mr : fmaxf(mr, rm);

      float a0 = 0.f, a1 = 0.f, a2 = 0.f, a3 = 0.f;
#pragma unroll
      for (int r = 0; r < 8; ++r) {
        float p0 = ex2(pv[0][r] - mn);      pv[0][r] = p0;      a0 += p0;
        float p1 = ex2(pv[0][8 + r] - mn);  pv[0][8 + r] = p1;  a1 += p1;
        float p2 = ex2(pv[1][r] - mn);      pv[1][r] = p2;      a2 += p2;
        float p3 = ex2(pv[1][8 + r] - mn);  pv[1][8 + r] = p3;  a3 += p3;
      }
      float ls = (a0 + a1) + (a2 + a3);
      ls += __shfl_xor(ls, 32);

      if (!defer) {
        const float alpha = ex2(mr - mn);
        lr = lr * alpha + ls;
        mr = mn;
#pragma unroll
        for (int r = 0; r < 16; ++r) {
          const int crow = (r & 3) + 8 * (r >> 2) + 4 * hi;
          const float ar = __shfl(alpha, crow | (lane & 32));
          oa[0][r] *= ar;
          oa[1][r] *= ar;
        }
      } else {
        lr += ls;
      }

      bf16x8 pa[4];
#pragma unroll
      for (int kb = 0; kb < 2; ++kb) {
        unsigned pk[8], ex[8];
#pragma unroll
        for (int i2 = 0; i2 < 8; ++i2)
          pk[i2] = cvt_pk_bf16(pv[kb][2 * i2], pv[kb][2 * i2 + 1]);
#pragma unroll
        for (int i2 = 0; i2 < 8; ++i2)
          ex[i2] = (unsigned)__shfl_xor((int)pk[i2], 32);
        union { unsigned u[4]; bf16x8 v8; } f0, f1;
        f0.u[0] = hi ? ex[2] : pk[0];
        f0.u[1] = hi ? ex[3] : pk[1];
        f0.u[2] = hi ? pk[2] : ex[0];
        f0.u[3] = hi ? pk[3] : ex[1];
        f1.u[0] = hi ? ex[6] : pk[4];
        f1.u[1] = hi ? ex[7] : pk[5];
        f1.u[2] = hi ? pk[6] : ex[4];
        f1.u[3] = hi ? pk[7] : ex[5];
        pa[2 * kb]     = f0.v8;
        pa[2 * kb + 1] = f1.v8;
      }

#pragma unroll
      for (int s = 0; s < 4; ++s) {
        const int g = ((s << 1) | hi) ^ (l31 & 7);
        bf16x8 vf0 = *(const bf16x8*)&Vs[cur][l31 * 64 + 8 * g];
        bf16x8 vf1 = *(const bf16x8*)&Vs[cur][(32 + l31) * 64 + 8 * g];
        oa[0] = __builtin_amdgcn_mfma_f32_32x32x16_bf16(pa[s], vf0, oa[0], 0, 0, 0);
        oa[1] = __builtin_amdgcn_mfma_f32_32x32x16_bf16(pa[s], vf1, oa[1], 0, 0, 0);
      }
    }

    asm volatile("s_waitcnt lgkmcnt(0)" ::: "memory");
    __builtin_amdgcn_s_barrier();
  }

  const float linv = rcp(lr);
#pragma unroll
  for (int r = 0; r < 16; ++r) {
    const int crow = (r & 3) + 8 * (r >> 2) + 4 * hi;
    const float li = __shfl(linv, crow | (lane & 32));
    const long row = qw + crow;
    og[obase + row * D + l31]      = f2bf(oa[0][r] * li);
    og[obase + row * D + 32 + l31] = f2bf(oa[1][r] * li);
  }
}

// ------------------------------- launcher -----------------------------------
extern "C" void kernel_launch(void* const* d_in, const int* in_sizes, int n_in,
                              void* d_out, int out_size, void* d_ws, size_t ws_size,
                              hipStream_t stream) {
  (void)in_sizes; (void)n_in; (void)out_size; (void)ws_size;
  const float* h     = (const float*)d_in[0];
  const float* ln1_g = (const float*)d_in[1];
  const float* ln1_b = (const float*)d_in[2];
  const float* wq    = (const float*)d_in[3];
  const float* bq    = (const float*)d_in[4];
  const float* wk    = (const float*)d_in[5];
  const float* bk    = (const float*)d_in[6];
  const float* wv    = (const float*)d_in[7];
  const float* bv    = (const float*)d_in[8];
  const float* wo    = (const float*)d_in[9];
  const float* bo    = (const float*)d_in[10];
  const float* ln2_g = (const float*)d_in[11];
  const float* ln2_b = (const float*)d_in[12];
  const float* wfc   = (const float*)d_in[13];
  const float* bfc   = (const float*)d_in[14];
  const float* wproj = (const float*)d_in[15];
  const float* bproj = (const float*)d_in[16];

  const int B = 4, S = 2048, D = 1024, H = 16, F = 4096, T = B * S;
  const int D3 = 3 * D;

  char* ws = (char*)d_ws;
  size_t off = 0;
  auto alloc = [&](size_t bytes) {
    void* p = ws + off;
    off += (bytes + 255) & ~(size_t)255;
    return p;
  };
  short* xb   = (short*)alloc((size_t)T * D * 2);     // ln1(x) / ln2(x)
  short* qkv  = (short*)alloc((size_t)T * D3 * 2);    // fused QKV out [T,3D]
  short* ob   = (short*)alloc((size_t)T * D * 2);     // attn out
  float* h2   = (float*)alloc((size_t)T * D * 4);     // post-attn residual
  short* wqkvb  = (short*)alloc((size_t)D3 * D * 2);
  short* wob    = (short*)alloc((size_t)D * D * 2);
  short* wfcb   = (short*)alloc((size_t)F * D * 2);
  short* wprojb = (short*)alloc((size_t)D * F * 2);
  float* bqkv   = (float*)alloc((size_t)D3 * 4);
  short* ub  = qkv;           // u [T,F]=64MB aliases qkv(48MB)+ob(16MB), dead by FC
  short* vtg = (short*)h2;    // V^T [B*H*64, S] aliases h2 (dead before Wo writes h2)

  W6 wargs;
  const int nqq = D * D / 4;
  wargs.s[0] = wq;    wargs.d[0] = wqkvb;
  wargs.s[1] = wk;    wargs.d[1] = wqkvb + (size_t)D * D;
  wargs.s[2] = wv;    wargs.d[2] = wqkvb + (size_t)2 * D * D;
  wargs.s[3] = wo;    wargs.d[3] = wob;
  wargs.s[4] = wfc;   wargs.d[4] = wfcb;
  wargs.s[5] = wproj; wargs.d[5] = wprojb;
  wargs.off[0] = 0;
  wargs.off[1] = nqq;
  wargs.off[2] = 2 * nqq;
  wargs.off[3] = 3 * nqq;
  wargs.off[4] = 4 * nqq;
  wargs.off[5] = 4 * nqq + F * D / 4;
  wargs.off[6] = 4 * nqq + 2 * (F * D / 4);
  cvt_all<<<dim3(wargs.off[6] / 256), 256, 0, stream>>>(wargs);
  hipMemcpyAsync(bqkv,         bq, D * 4, hipMemcpyDeviceToDevice, stream);
  hipMemcpyAsync(bqkv + D,     bk, D * 4, hipMemcpyDeviceToDevice, stream);
  hipMemcpyAsync(bqkv + 2 * D, bv, D * 4, hipMemcpyDeviceToDevice, stream);

  // attention sub-block
  ln_fwd<<<dim3(T), 256, 0, stream>>>(h, ln1_g, ln1_b, xb);
  gemm256b<1, 0, 0, 1><<<dim3((T / 256) * (D3 / 256)), 512, 0, stream>>>(
      xb, wqkvb, bqkv, nullptr, qkv, T, D3, D);
  transpose_v<<<dim3(S / 64, B * H), 256, 0, stream>>>(qkv + 2 * D, vtg, S, D3, H);
  attn_fwd2<<<dim3((S / 128) * (B * H / 64) * 64), 256, 0, stream>>>(
      qkv, qkv + D, vtg, ob, S, D3, D, H);
  gemm_bt6<0, 1, 0><<<dim3((T / 128) * (D / 128)), 256, 0, stream>>>(
      ob, wob, bo, h, h2, T, D, D);

  // MLP sub-block
  ln_fwd<<<dim3(T), 256, 0, stream>>>(h2, ln2_g, ln2_b, xb);
  gemm256b<1, 0, 1, 0><<<dim3((T / 256) * (F / 256)), 512, 0, stream>>>(
      xb, wfcb, bfc, nullptr, ub, T, F, D);
  gemm_bt6<0, 1, 0><<<dim3((T / 128) * (D / 128)), 256, 0, stream>>>(
      ub, wprojb, bproj, h2, (float*)d_out, T, D, F);
}

// Round 15
// 368.689 us; speedup vs baseline: 1.0636x; 1.0636x over previous
//
#include <hip/hip_runtime.h>
#include <hip/hip_bf16.h>
#include <stdint.h>

// ---------------------------------------------------------------------------
// GPT-2 block on MI355X (gfx950). Round 15:
//  Round-13 state (373us, best) + V-transpose fused into the QKV GEMM
//  epilogue: V-third blocks write acc directly transposed into vtg (8B
//  s16x4 stores of 4 consecutive tokens per dh-row); transpose_v kernel and
//  the V row-major write are dropped. gemm256b (r14, regressed) abandoned.
// ---------------------------------------------------------------------------

typedef short bf16x8 __attribute__((ext_vector_type(8)));
typedef float f32x4  __attribute__((ext_vector_type(4)));
typedef float f32x16 __attribute__((ext_vector_type(16)));
typedef short s16x4  __attribute__((ext_vector_type(4)));

__device__ __forceinline__ short f2bf(float f) {
  union { float f; uint32_t u; } a;
  a.f = f;
  uint32_t r = a.u + 0x7fffu + ((a.u >> 16) & 1u);  // RNE
  return (short)(r >> 16);
}

__device__ __forceinline__ unsigned cvt_pk_bf16(float lo, float hi_) {
  unsigned r;
  asm("v_cvt_pk_bf16_f32 %0, %1, %2" : "=v"(r) : "v"(lo), "v"(hi_));
  return r;
}

__device__ __forceinline__ float ex2(float x) {   // D = 2^x, raw HW op
  float r;
  asm("v_exp_f32 %0, %1" : "=v"(r) : "v"(x));
  return r;
}

__device__ __forceinline__ float rcp(float x) {
  float r;
  asm("v_rcp_f32 %0, %1" : "=v"(r) : "v"(x));
  return r;
}

__device__ __forceinline__ float m3(float a, float b, float c) {
  return fmaxf(fmaxf(a, b), c);   // clang fuses to v_max3_f32
}

__device__ __forceinline__ void gload_lds16(const void* g, void* l) {
  __builtin_amdgcn_global_load_lds(
      (const __attribute__((address_space(1))) void*)g,
      (__attribute__((address_space(3))) void*)l, 16, 0, 0);
}

__device__ __forceinline__ float gelu_f(float x) {
  float y = 0.7978845608028654f * (x + 0.044715f * x * x * x);
  y = fminf(fmaxf(y, -20.f), 20.f);
  float e = __expf(2.f * y);
  return 0.5f * x * (1.f + (e - 1.f) / (e + 1.f));  // tanh via exp
}

// ---------------------- merged weight fp32 -> bf16 --------------------------
struct W6 {
  const float* s[6];
  short* d[6];
  int off[7];   // prefix offsets in float4 units
};

__global__ __launch_bounds__(256)
void cvt_all(W6 a) {
  const int i = blockIdx.x * 256 + threadIdx.x;
#pragma unroll
  for (int k = 0; k < 6; ++k) {
    if (i >= a.off[k] && i < a.off[k + 1]) {
      const int j = i - a.off[k];
      float4 v = ((const float4*)a.s[k])[j];
      s16x4 o;
      o[0] = f2bf(v.x); o[1] = f2bf(v.y); o[2] = f2bf(v.z); o[3] = f2bf(v.w);
      ((s16x4*)a.d[k])[j] = o;
    }
  }
}

// ------------------------------- LayerNorm ---------------------------------
__global__ __launch_bounds__(256)
void ln_fwd(const float* __restrict__ x, const float* __restrict__ g,
            const float* __restrict__ b, short* __restrict__ y) {
  const long row = blockIdx.x;
  const int t = threadIdx.x;
  const float4 xv = ((const float4*)(x + row * 1024))[t];
  float s  = xv.x + xv.y + xv.z + xv.w;
  float ss = xv.x * xv.x + xv.y * xv.y + xv.z * xv.z + xv.w * xv.w;
#pragma unroll
  for (int m = 1; m < 64; m <<= 1) {
    s  += __shfl_xor(s, m);
    ss += __shfl_xor(ss, m);
  }
  __shared__ float rs[4], rss[4];
  const int wid = t >> 6, lane = t & 63;
  if (lane == 0) { rs[wid] = s; rss[wid] = ss; }
  __syncthreads();
  s  = rs[0] + rs[1] + rs[2] + rs[3];
  ss = rss[0] + rss[1] + rss[2] + rss[3];
  const float mu   = s * (1.f / 1024.f);
  const float var  = ss * (1.f / 1024.f) - mu * mu;
  const float rstd = rsqrtf(var + 1e-5f);
  const float4 gv = ((const float4*)g)[t];
  const float4 bv = ((const float4*)b)[t];
  s16x4 ov;
  ov[0] = f2bf((xv.x - mu) * rstd * gv.x + bv.x);
  ov[1] = f2bf((xv.y - mu) * rstd * gv.y + bv.y);
  ov[2] = f2bf((xv.z - mu) * rstd * gv.z + bv.z);
  ov[3] = f2bf((xv.w - mu) * rstd * gv.w + bv.w);
  *(s16x4*)(y + row * 1024 + t * 4) = ov;
}

// -------------- GEMM 128x256 (NT, BK=64, single-buf, 64x128/wave) -----------
// SCALE_Q: first N/3 output cols scaled by 1/8*log2e (QKV only).
// V_TRANS: blocks with bcol >= 2*(N/3) write transposed into vtg (V third);
//          row-major write skipped for those blocks.
template <int OUT_BF16, int HAS_RES, int HAS_GELU, int SCALE_Q, int V_TRANS>
__global__ __launch_bounds__(256, 2)
void gemm_bt5(const short* __restrict__ A, const short* __restrict__ W,
              const float* __restrict__ bias, const float* __restrict__ res,
              void* __restrict__ out, int M, int N, int K,
              short* __restrict__ vtg, int Sp, int Hp) {
  __shared__ short As[128 * 64];
  __shared__ short Bs[256 * 64];
  const int tid = threadIdx.x;
  const int wid = tid >> 6, lane = tid & 63;
  const int l16 = lane & 15, lg = lane >> 4;
  const int wm = wid >> 1, wn = wid & 1;       // 2 x 2 wave grid

  const int nbx = N >> 8;
  const int nwg = nbx * (M >> 7);
  int flat = (int)blockIdx.x;
  if ((nwg & 7) == 0) flat = (flat & 7) * (nwg >> 3) + (flat >> 3);
  const int brow = (flat / nbx) * 128, bcol = (flat % nbx) * 256;

  f32x4 acc[4][8] = {};

  const int r0 = tid >> 3, g0 = tid & 7;

  int ra[4], rb[8];
#pragma unroll
  for (int m = 0; m < 4; ++m) ra[m] = wm * 64 + m * 16 + l16;
#pragma unroll
  for (int n = 0; n < 8; ++n) rb[n] = wn * 128 + n * 16 + l16;

  for (int kt = 0; kt < K; kt += 64) {
    __syncthreads();
#pragma unroll
    for (int i = 0; i < 4; ++i) {
      const int row = i * 32 + r0;
      gload_lds16(A + (long)(brow + row) * K + kt + 8 * (g0 ^ (row & 7)),
                  &As[(i * 256 + tid) * 8]);
    }
#pragma unroll
    for (int i = 0; i < 8; ++i) {
      const int row = i * 32 + r0;
      gload_lds16(W + (long)(bcol + row) * K + kt + 8 * (g0 ^ (row & 7)),
                  &Bs[(i * 256 + tid) * 8]);
    }
    __syncthreads();

#pragma unroll
    for (int kk = 0; kk < 2; ++kk) {
      bf16x8 af[4], bf[8];
#pragma unroll
      for (int m = 0; m < 4; ++m)
        af[m] = *(const bf16x8*)&As[ra[m] * 64 + 8 * ((kk * 4 + lg) ^ (ra[m] & 7))];
#pragma unroll
      for (int n = 0; n < 8; ++n)
        bf[n] = *(const bf16x8*)&Bs[rb[n] * 64 + 8 * ((kk * 4 + lg) ^ (rb[n] & 7))];
#pragma unroll
      for (int m = 0; m < 4; ++m)
#pragma unroll
        for (int n = 0; n < 8; ++n)
          acc[m][n] = __builtin_amdgcn_mfma_f32_16x16x32_bf16(af[m], bf[n], acc[m][n], 0, 0, 0);
    }
  }

  if (V_TRANS && bcol >= 2 * (N / 3)) {
    // V third: write transposed. token = brow + wm*64 + m*16 + lg*4 + j.
    const int bidx = brow / Sp;                  // batch (tile never crosses b)
    const int s0 = brow - bidx * Sp + wm * 64;
#pragma unroll
    for (int n = 0; n < 8; ++n) {
      const int col = bcol + wn * 128 + n * 16 + l16;
      const int c1 = col - 2 * (N / 3);
      const int hh = c1 >> 6, dh = c1 & 63;
      const float bb = bias[col];
      short* dst = vtg + ((long)(bidx * Hp + hh) * 64 + dh) * Sp + s0;
#pragma unroll
      for (int m = 0; m < 4; ++m) {
        s16x4 ov;
#pragma unroll
        for (int j = 0; j < 4; ++j) ov[j] = f2bf(acc[m][n][j] + bb);
        *(s16x4*)(dst + m * 16 + lg * 4) = ov;
      }
    }
    return;
  }

#pragma unroll
  for (int n = 0; n < 8; ++n) {
    const int col = bcol + wn * 128 + n * 16 + l16;
    const float bb = bias[col];
    const bool doScale = SCALE_Q && (col < N / 3);
#pragma unroll
    for (int m = 0; m < 4; ++m) {
#pragma unroll
      for (int j = 0; j < 4; ++j) {
        const long row = brow + wm * 64 + m * 16 + lg * 4 + j;
        float vv = acc[m][n][j] + bb;
        if (HAS_GELU) vv = gelu_f(vv);
        if (HAS_RES) vv += res[row * N + col];
        if (SCALE_Q && doScale) vv *= 0.18033688f;   // 1/8 * log2(e)
        if (OUT_BF16) ((short*)out)[row * N + col] = f2bf(vv);
        else          ((float*)out)[row * N + col] = vv;
      }
    }
  }
}

// -------------- GEMM 128x128 (NT, BK=64, single-buf, 64x64/wave) ------------
template <int OUT_BF16, int HAS_RES, int HAS_GELU>
__global__ __launch_bounds__(256, 2)
void gemm_bt6(const short* __restrict__ A, const short* __restrict__ W,
              const float* __restrict__ bias, const float* __restrict__ res,
              void* __restrict__ out, int M, int N, int K) {
  __shared__ short As[128 * 64];
  __shared__ short Bs[128 * 64];
  const int tid = threadIdx.x;
  const int wid = tid >> 6, lane = tid & 63;
  const int l16 = lane & 15, lg = lane >> 4;
  const int wm = wid >> 1, wn = wid & 1;       // 2 x 2 wave grid

  const int nbx = N >> 7;
  const int nwg = nbx * (M >> 7);
  int flat = (int)blockIdx.x;
  if ((nwg & 7) == 0) flat = (flat & 7) * (nwg >> 3) + (flat >> 3);
  const int brow = (flat / nbx) * 128, bcol = (flat % nbx) * 128;

  f32x4 acc[4][4] = {};

  const int r0 = tid >> 3, g0 = tid & 7;

  int ra[4], rb[4];
#pragma unroll
  for (int m = 0; m < 4; ++m) ra[m] = wm * 64 + m * 16 + l16;
#pragma unroll
  for (int n = 0; n < 4; ++n) rb[n] = wn * 64 + n * 16 + l16;

  for (int kt = 0; kt < K; kt += 64) {
    __syncthreads();
#pragma unroll
    for (int i = 0; i < 4; ++i) {
      const int row = i * 32 + r0;
      gload_lds16(A + (long)(brow + row) * K + kt + 8 * (g0 ^ (row & 7)),
                  &As[(i * 256 + tid) * 8]);
      gload_lds16(W + (long)(bcol + row) * K + kt + 8 * (g0 ^ (row & 7)),
                  &Bs[(i * 256 + tid) * 8]);
    }
    __syncthreads();

#pragma unroll
    for (int kk = 0; kk < 2; ++kk) {
      bf16x8 af[4], bf[4];
#pragma unroll
      for (int m = 0; m < 4; ++m)
        af[m] = *(const bf16x8*)&As[ra[m] * 64 + 8 * ((kk * 4 + lg) ^ (ra[m] & 7))];
#pragma unroll
      for (int n = 0; n < 4; ++n)
        bf[n] = *(const bf16x8*)&Bs[rb[n] * 64 + 8 * ((kk * 4 + lg) ^ (rb[n] & 7))];
#pragma unroll
      for (int m = 0; m < 4; ++m)
#pragma unroll
        for (int n = 0; n < 4; ++n)
          acc[m][n] = __builtin_amdgcn_mfma_f32_16x16x32_bf16(af[m], bf[n], acc[m][n], 0, 0, 0);
    }
  }

#pragma unroll
  for (int n = 0; n < 4; ++n) {
    const int col = bcol + wn * 64 + n * 16 + l16;
    const float bb = bias[col];
#pragma unroll
    for (int m = 0; m < 4; ++m) {
#pragma unroll
      for (int j = 0; j < 4; ++j) {
        const long row = brow + wm * 64 + m * 16 + lg * 4 + j;
        float vv = acc[m][n][j] + bb;
        if (HAS_GELU) vv = gelu_f(vv);
        if (HAS_RES) vv += res[row * N + col];
        if (OUT_BF16) ((short*)out)[row * N + col] = f2bf(vv);
        else          ((float*)out)[row * N + col] = vv;
      }
    }
  }
}

// --------------------------- causal flash attention -------------------------
// Q pre-scaled by 1/8*log2e. v_max3 tree + raw v_exp_f32; scalar lr;
// shuffle epilogue with v_rcp.
__global__ __launch_bounds__(256, 4)
void attn_fwd2(const short* __restrict__ qg, const short* __restrict__ kg,
               const short* __restrict__ vtg, short* __restrict__ og,
               int S, int ldq, int D, int H) {
  const int tid = threadIdx.x, wid = tid >> 6, lane = tid & 63;
  const int l31 = lane & 31, hi = lane >> 5;
  const int fid = blockIdx.x;
  const int bh = fid & 63;
  const int b = bh / H, hh = bh % H;
  static const int perm[16] = {15, 0, 8, 7, 1, 14, 6, 9, 13, 2, 10, 5, 3, 12, 4, 11};
  const int qt = perm[(fid >> 6) & 15];
  const int q0 = qt * 128;
  const long qbase = (long)b * S * ldq + hh * 64;
  const long obase = (long)b * S * D + hh * 64;
  const long vbase = (long)bh * 64 * S;

  __shared__ short Ks[2][64 * 64];
  __shared__ short Vs[2][64 * 64];

  auto STAGE = [&](int buf, int k0) {
#pragma unroll
    for (int i = 0; i < 2; ++i) {
      const int c = i * 256 + tid;
      const int row = c >> 3, gl = c & 7;
      gload_lds16(&kg[qbase + (long)(k0 + row) * ldq + 8 * (gl ^ (row & 7))],
                  &Ks[buf][(i * 256 + wid * 64) * 8]);
      gload_lds16(&vtg[vbase + (long)row * S + k0 + 8 * (gl ^ (row & 7))],
                  &Vs[buf][(i * 256 + wid * 64) * 8]);
    }
  };

  const int qw = q0 + wid * 32;
  const int qv = qw + l31;

  bf16x8 qf[4];
#pragma unroll
  for (int s = 0; s < 4; ++s)
    qf[s] = *(const bf16x8*)&qg[qbase + (long)qv * ldq + 16 * s + 8 * hi];

  f32x16 oa[2] = {};
  float mr = -3000.f, lr = 0.f;

  const int ntiles = qt * 2 + 2;

  STAGE(0, 0);
  for (int t = 0; t < ntiles; ++t) {
    const int cur = t & 1;
    const int k0 = t * 64;
    if (t + 1 < ntiles) {
      STAGE(cur ^ 1, k0 + 64);
      asm volatile("s_waitcnt vmcnt(4)" ::: "memory");
    } else {
      asm volatile("s_waitcnt vmcnt(0)" ::: "memory");
    }
    __builtin_amdgcn_s_barrier();

    if (k0 < qw + 32) {
      f32x16 st[2] = {};
#pragma unroll
      for (int s = 0; s < 4; ++s) {
        const int g = ((s << 1) | hi) ^ (l31 & 7);
        bf16x8 kf0 = *(const bf16x8*)&Ks[cur][l31 * 64 + 8 * g];
        bf16x8 kf1 = *(const bf16x8*)&Ks[cur][(32 + l31) * 64 + 8 * g];
        st[0] = __builtin_amdgcn_mfma_f32_32x32x16_bf16(kf0, qf[s], st[0], 0, 0, 0);
        st[1] = __builtin_amdgcn_mfma_f32_32x32x16_bf16(kf1, qf[s], st[1], 0, 0, 0);
      }

      const bool need_mask = (k0 + 63 > qw);
      float pv[2][16];
#pragma unroll
      for (int kb = 0; kb < 2; ++kb)
#pragma unroll
        for (int r = 0; r < 16; ++r) {
          float v = st[kb][r];           // Q pre-scaled: log2 domain
          if (need_mask) {
            const int key = k0 + kb * 32 + (r & 3) + 8 * (r >> 2) + 4 * hi;
            if (key > qv) v = -1e30f;
          }
          pv[kb][r] = v;
        }

      float rm = fmaxf(pv[0][0], pv[0][1]);
#pragma unroll
      for (int r = 2; r < 16; r += 2) rm = m3(rm, pv[0][r], pv[0][r + 1]);
#pragma unroll
      for (int r = 0; r < 16; r += 2) rm = m3(rm, pv[1][r], pv[1][r + 1]);
      rm = fmaxf(rm, __shfl_xor(rm, 32));

      const bool defer = (bool)__all(rm <= mr + 8.f);
      const float mn = defer ? mr : fmaxf(mr, rm);

      float a0 = 0.f, a1 = 0.f, a2 = 0.f, a3 = 0.f;
#pragma unroll
      for (int r = 0; r < 8; ++r) {
        float p0 = ex2(pv[0][r] - mn);      pv[0][r] = p0;      a0 += p0;
        float p1 = ex2(pv[0][8 + r] - mn);  pv[0][8 + r] = p1;  a1 += p1;
        float p2 = ex2(pv[1][r] - mn);      pv[1][r] = p2;      a2 += p2;
        float p3 = ex2(pv[1][8 + r] - mn);  pv[1][8 + r] = p3;  a3 += p3;
      }
      float ls = (a0 + a1) + (a2 + a3);
      ls += __shfl_xor(ls, 32);

      if (!defer) {
        const float alpha = ex2(mr - mn);
        lr = lr * alpha + ls;
        mr = mn;
#pragma unroll
        for (int r = 0; r < 16; ++r) {
          const int crow = (r & 3) + 8 * (r >> 2) + 4 * hi;
          const float ar = __shfl(alpha, crow | (lane & 32));
          oa[0][r] *= ar;
          oa[1][r] *= ar;
        }
      } else {
        lr += ls;
      }

      bf16x8 pa[4];
#pragma unroll
      for (int kb = 0; kb < 2; ++kb) {
        unsigned pk[8], ex[8];
#pragma unroll
        for (int i2 = 0; i2 < 8; ++i2)
          pk[i2] = cvt_pk_bf16(pv[kb][2 * i2], pv[kb][2 * i2 + 1]);
#pragma unroll
        for (int i2 = 0; i2 < 8; ++i2)
          ex[i2] = (unsigned)__shfl_xor((int)pk[i2], 32);
        union { unsigned u[4]; bf16x8 v8; } f0, f1;
        f0.u[0] = hi ? ex[2] : pk[0];
        f0.u[1] = hi ? ex[3] : pk[1];
        f0.u[2] = hi ? pk[2] : ex[0];
        f0.u[3] = hi ? pk[3] : ex[1];
        f1.u[0] = hi ? ex[6] : pk[4];
        f1.u[1] = hi ? ex[7] : pk[5];
        f1.u[2] = hi ? pk[6] : ex[4];
        f1.u[3] = hi ? pk[7] : ex[5];
        pa[2 * kb]     = f0.v8;
        pa[2 * kb + 1] = f1.v8;
      }

#pragma unroll
      for (int s = 0; s < 4; ++s) {
        const int g = ((s << 1) | hi) ^ (l31 & 7);
        bf16x8 vf0 = *(const bf16x8*)&Vs[cur][l31 * 64 + 8 * g];
        bf16x8 vf1 = *(const bf16x8*)&Vs[cur][(32 + l31) * 64 + 8 * g];
        oa[0] = __builtin_amdgcn_mfma_f32_32x32x16_bf16(pa[s], vf0, oa[0], 0, 0, 0);
        oa[1] = __builtin_amdgcn_mfma_f32_32x32x16_bf16(pa[s], vf1, oa[1], 0, 0, 0);
      }
    }

    asm volatile("s_waitcnt lgkmcnt(0)" ::: "memory");
    __builtin_amdgcn_s_barrier();
  }

  const float linv = rcp(lr);
#pragma unroll
  for (int r = 0; r < 16; ++r) {
    const int crow = (r & 3) + 8 * (r >> 2) + 4 * hi;
    const float li = __shfl(linv, crow | (lane & 32));
    const long row = qw + crow;
    og[obase + row * D + l31]      = f2bf(oa[0][r] * li);
    og[obase + row * D + 32 + l31] = f2bf(oa[1][r] * li);
  }
}

// ------------------------------- launcher -----------------------------------
extern "C" void kernel_launch(void* const* d_in, const int* in_sizes, int n_in,
                              void* d_out, int out_size, void* d_ws, size_t ws_size,
                              hipStream_t stream) {
  (void)in_sizes; (void)n_in; (void)out_size; (void)ws_size;
  const float* h     = (const float*)d_in[0];
  const float* ln1_g = (const float*)d_in[1];
  const float* ln1_b = (const float*)d_in[2];
  const float* wq    = (const float*)d_in[3];
  const float* bq    = (const float*)d_in[4];
  const float* wk    = (const float*)d_in[5];
  const float* bk    = (const float*)d_in[6];
  const float* wv    = (const float*)d_in[7];
  const float* bv    = (const float*)d_in[8];
  const float* wo    = (const float*)d_in[9];
  const float* bo    = (const float*)d_in[10];
  const float* ln2_g = (const float*)d_in[11];
  const float* ln2_b = (const float*)d_in[12];
  const float* wfc   = (const float*)d_in[13];
  const float* bfc   = (const float*)d_in[14];
  const float* wproj = (const float*)d_in[15];
  const float* bproj = (const float*)d_in[16];

  const int B = 4, S = 2048, D = 1024, H = 16, F = 4096, T = B * S;
  const int D3 = 3 * D;

  char* ws = (char*)d_ws;
  size_t off = 0;
  auto alloc = [&](size_t bytes) {
    void* p = ws + off;
    off += (bytes + 255) & ~(size_t)255;
    return p;
  };
  short* xb   = (short*)alloc((size_t)T * D * 2);     // ln1(x) / ln2(x)
  short* qkv  = (short*)alloc((size_t)T * D3 * 2);    // fused QKV out [T,3D]
  short* ob   = (short*)alloc((size_t)T * D * 2);     // attn out
  float* h2   = (float*)alloc((size_t)T * D * 4);     // post-attn residual
  short* wqkvb  = (short*)alloc((size_t)D3 * D * 2);
  short* wob    = (short*)alloc((size_t)D * D * 2);
  short* wfcb   = (short*)alloc((size_t)F * D * 2);
  short* wprojb = (short*)alloc((size_t)D * F * 2);
  float* bqkv   = (float*)alloc((size_t)D3 * 4);
  short* ub  = qkv;           // u [T,F]=64MB aliases qkv(48MB)+ob(16MB), dead by FC
  short* vtg = (short*)h2;    // V^T [B*H*64, S] aliases h2 (dead before Wo writes h2)

  W6 wargs;
  const int nqq = D * D / 4;
  wargs.s[0] = wq;    wargs.d[0] = wqkvb;
  wargs.s[1] = wk;    wargs.d[1] = wqkvb + (size_t)D * D;
  wargs.s[2] = wv;    wargs.d[2] = wqkvb + (size_t)2 * D * D;
  wargs.s[3] = wo;    wargs.d[3] = wob;
  wargs.s[4] = wfc;   wargs.d[4] = wfcb;
  wargs.s[5] = wproj; wargs.d[5] = wprojb;
  wargs.off[0] = 0;
  wargs.off[1] = nqq;
  wargs.off[2] = 2 * nqq;
  wargs.off[3] = 3 * nqq;
  wargs.off[4] = 4 * nqq;
  wargs.off[5] = 4 * nqq + F * D / 4;
  wargs.off[6] = 4 * nqq + 2 * (F * D / 4);
  cvt_all<<<dim3(wargs.off[6] / 256), 256, 0, stream>>>(wargs);
  hipMemcpyAsync(bqkv,         bq, D * 4, hipMemcpyDeviceToDevice, stream);
  hipMemcpyAsync(bqkv + D,     bk, D * 4, hipMemcpyDeviceToDevice, stream);
  hipMemcpyAsync(bqkv + 2 * D, bv, D * 4, hipMemcpyDeviceToDevice, stream);

  // attention sub-block (V transposed directly by the QKV epilogue)
  ln_fwd<<<dim3(T), 256, 0, stream>>>(h, ln1_g, ln1_b, xb);
  gemm_bt5<1, 0, 0, 1, 1><<<dim3((T / 128) * (D3 / 256)), 256, 0, stream>>>(
      xb, wqkvb, bqkv, nullptr, qkv, T, D3, D, vtg, S, H);
  attn_fwd2<<<dim3((S / 128) * (B * H / 64) * 64), 256, 0, stream>>>(
      qkv, qkv + D, vtg, ob, S, D3, D, H);
  gemm_bt6<0, 1, 0><<<dim3((T / 128) * (D / 128)), 256, 0, stream>>>(
      ob, wob, bo, h, h2, T, D, D);

  // MLP sub-block
  ln_fwd<<<dim3(T), 256, 0, stream>>>(h2, ln2_g, ln2_b, xb);
  gemm_bt5<1, 0, 1, 0, 0><<<dim3((T / 128) * (F / 256)), 256, 0, stream>>>(
      xb, wfcb, bfc, nullptr, ub, T, F, D, nullptr, 0, 0);
  gemm_bt6<0, 1, 0><<<dim3((T / 128) * (D / 128)), 256, 0, stream>>>(
      ub, wprojb, bproj, h2, (float*)d_out, T, D, F);
}